// Round 1
// baseline (547.421 us; speedup 1.0000x reference)
//
#include <hip/hip_runtime.h>

#define BN_EPS 1e-5f

// ---------------- Haar DWT: (B,C,H,W) -> (B,4C,H/2,W/2), channel = c*4+s ----
__global__ __launch_bounds__(256) void dwt_kernel(
    const float* __restrict__ in, float* __restrict__ out,
    int B, int C, int H, int W)
{
  int H2 = H >> 1, W2 = W >> 1;
  long total = (long)B * C * H2 * W2;
  long idx = (long)blockIdx.x * 256 + threadIdx.x;
  if (idx >= total) return;
  int w2 = (int)(idx % W2); long t = idx / W2;
  int h2 = (int)(t % H2); t /= H2;
  int c = (int)(t % C); int b = (int)(t / C);
  const float* p = in + (((long)(b * C + c) * H + 2 * h2) * W + 2 * w2);
  float a  = p[0], bb = p[1];
  float cc = p[W], dd = p[W + 1];
  float ll = (a + bb + cc + dd) * 0.5f;
  float lh = (a + bb - cc - dd) * 0.5f;
  float hl = (a - bb + cc - dd) * 0.5f;
  float hh = (a - bb - cc + dd) * 0.5f;
  long cs = (long)H2 * W2;
  float* q = out + ((long)(b * 4 * C + c * 4)) * cs + (long)h2 * W2 + w2;
  q[0] = ll; q[cs] = lh; q[2 * cs] = hl; q[3 * cs] = hh;
}

// ------------- ConvTranspose2d(k=4,s=2,p=1) + BN + ReLU ---------------------
// out[n,co,oh,ow] = relu(bn(sum_{ci,kh,kw} in[n,ci,ih,iw]*w[ci,co,kh,kw] + b))
// with oh = 2*ih - 1 + kh. Per output parity: 2 row-taps x 2 col-taps.
// Block: 8 co x 32x32 outputs; thread: 2 co x 4x4 outputs.
template<int CIN, int CI_CHUNK, int HIN, int WIN>
__global__ __launch_bounds__(256, 2) void convt_bn_relu_kernel(
    const float* __restrict__ in,    // (B, CIN, HIN, WIN)
    const float* __restrict__ wgt,   // (CIN, 48, 4, 4)
    const float* __restrict__ bias,  // (48)
    const float* __restrict__ gam,
    const float* __restrict__ bet,
    const float* __restrict__ mu,
    const float* __restrict__ var,
    float* __restrict__ out,         // (B, outc_total, 2HIN, 2WIN), base obase
    int outc_total, int obase)
{
  constexpr int COUT = 48;
  constexpr int HOUT = 2 * HIN, WOUT = 2 * WIN;
  constexpr int IT = 18;  // 16 quads + 2 border rows/cols
  __shared__ __align__(16) float in_lds[CI_CHUNK * IT * IT];
  __shared__ __align__(16) float w_lds[CI_CHUNK * 8 * 16];

  const int tid = threadIdx.x;
  const int n  = blockIdx.z / (COUT / 8);
  const int cb = blockIdx.z % (COUT / 8);
  const int co0 = cb * 8;
  const int OH0 = blockIdx.y * 32;
  const int OW0 = blockIdx.x * 32;
  const int qY0 = OH0 >> 1, qX0 = OW0 >> 1;

  const int co_grp = tid >> 6;     // wave-uniform: 0..3
  const int t64 = tid & 63;
  const int ty = t64 >> 3, tx = t64 & 7;

  float acc[2][4][4];
  #pragma unroll
  for (int a = 0; a < 2; ++a)
    #pragma unroll
    for (int b = 0; b < 4; ++b)
      #pragma unroll
      for (int c = 0; c < 4; ++c) acc[a][b][c] = 0.f;

  for (int ci0 = 0; ci0 < CIN; ci0 += CI_CHUNK) {
    __syncthreads();
    // stage input tile (zero-padded at image borders)
    for (int i = tid; i < CI_CHUNK * IT * IT; i += 256) {
      int ci = i / (IT * IT);
      int rem = i - ci * IT * IT;
      int r = rem / IT, cc = rem - r * IT;
      int ih = qY0 - 1 + r, iw = qX0 - 1 + cc;
      float val = 0.f;
      if ((unsigned)ih < (unsigned)HIN && (unsigned)iw < (unsigned)WIN)
        val = in[(((long)n * CIN + ci0 + ci) * HIN + ih) * WIN + iw];
      in_lds[i] = val;
    }
    // stage weights chunk: [ci][co(8)][16]
    for (int i = tid; i < CI_CHUNK * 128; i += 256) {
      int ci = i >> 7;
      int rem = i & 127;  // co*16 + k
      w_lds[i] = wgt[((ci0 + ci) * COUT + co0) * 16 + rem];
    }
    __syncthreads();

    #pragma unroll 4
    for (int ci = 0; ci < CI_CHUNK; ++ci) {
      float xin[4][4];
      const float* rb = &in_lds[ci * IT * IT + (2 * ty) * IT + 2 * tx];
      #pragma unroll
      for (int i = 0; i < 4; ++i) {
        float2 u0 = *(const float2*)(rb + i * IT);
        float2 u1 = *(const float2*)(rb + i * IT + 2);
        xin[i][0] = u0.x; xin[i][1] = u0.y; xin[i][2] = u1.x; xin[i][3] = u1.y;
      }
      #pragma unroll
      for (int c2 = 0; c2 < 2; ++c2) {
        const int co_l = co_grp * 2 + c2;
        const float4* wp = (const float4*)&w_lds[ci * 128 + co_l * 16];
        float4 wa = wp[0], wb = wp[1], wc = wp[2], wd = wp[3];
        const float wv[16] = {wa.x, wa.y, wa.z, wa.w, wb.x, wb.y, wb.z, wb.w,
                              wc.x, wc.y, wc.z, wc.w, wd.x, wd.y, wd.z, wd.w};
        #pragma unroll
        for (int yy = 0; yy < 4; ++yy) {
          const int qyl = yy >> 1, py = yy & 1;
          const int iA = qyl + (py ? 2 : 1);   // tap A: d=py?+1:0
          const int khA = py ? 0 : 1;
          const int iB = qyl + (py ? 1 : 0);   // tap B: d=py?0:-1
          const int khB = py ? 2 : 3;
          #pragma unroll
          for (int xx = 0; xx < 4; ++xx) {
            const int qxl = xx >> 1, px = xx & 1;
            const int jA = qxl + (px ? 2 : 1);
            const int kwA = px ? 0 : 1;
            const int jB = qxl + (px ? 1 : 0);
            const int kwB = px ? 2 : 3;
            float s = acc[c2][yy][xx];
            s += xin[iA][jA] * wv[khA * 4 + kwA];
            s += xin[iA][jB] * wv[khA * 4 + kwB];
            s += xin[iB][jA] * wv[khB * 4 + kwA];
            s += xin[iB][jB] * wv[khB * 4 + kwB];
            acc[c2][yy][xx] = s;
          }
        }
      }
    }
  }

  // epilogue: fold conv-bias into BN, ReLU, float4 stores
  #pragma unroll
  for (int c2 = 0; c2 < 2; ++c2) {
    const int co = co0 + co_grp * 2 + c2;
    const float inv = gam[co] * rsqrtf(var[co] + BN_EPS);
    const float sh  = (bias[co] - mu[co]) * inv + bet[co];
    #pragma unroll
    for (int yy = 0; yy < 4; ++yy) {
      const int oh = OH0 + 4 * ty + yy;
      float* op = out + (((long)n * outc_total + obase + co) * HOUT + oh) * WOUT
                  + OW0 + 4 * tx;
      float4 o;
      o.x = fmaxf(acc[c2][yy][0] * inv + sh, 0.f);
      o.y = fmaxf(acc[c2][yy][1] * inv + sh, 0.f);
      o.z = fmaxf(acc[c2][yy][2] * inv + sh, 0.f);
      o.w = fmaxf(acc[c2][yy][3] * inv + sh, 0.f);
      *(float4*)op = o;
    }
  }
}

extern "C" void kernel_launch(void* const* d_in, const int* in_sizes, int n_in,
                              void* d_out, int out_size, void* d_ws, size_t ws_size,
                              hipStream_t stream) {
  const float* x    = (const float*)d_in[0];
  const float* w1   = (const float*)d_in[1];
  const float* b1   = (const float*)d_in[2];
  const float* g1   = (const float*)d_in[3];
  const float* be1  = (const float*)d_in[4];
  const float* m1   = (const float*)d_in[5];
  const float* v1   = (const float*)d_in[6];
  const float* w2a  = (const float*)d_in[7];
  const float* b2a  = (const float*)d_in[8];
  const float* g2a  = (const float*)d_in[9];
  const float* be2a = (const float*)d_in[10];
  const float* m2a  = (const float*)d_in[11];
  const float* v2a  = (const float*)d_in[12];
  const float* w2b  = (const float*)d_in[13];
  const float* b2b  = (const float*)d_in[14];
  const float* g2b  = (const float*)d_in[15];
  const float* be2b = (const float*)d_in[16];
  const float* m2b  = (const float*)d_in[17];
  const float* v2b  = (const float*)d_in[18];

  float* out = (float*)d_out;
  float* xl1 = (float*)d_ws;                       // 16*12*128*128 = 3145728
  float* xl2 = xl1 + (long)16 * 12 * 128 * 128;    // 16*48*64*64   = 3145728
  float* o2a = xl2 + (long)16 * 48 * 64 * 64;      // 16*48*128*128 = 12582912

  // DWT level 1 and 2
  dwt_kernel<<<3072, 256, 0, stream>>>(x, xl1, 16, 3, 256, 256);
  dwt_kernel<<<3072, 256, 0, stream>>>(xl1, xl2, 16, 12, 128, 128);

  dim3 blk(256);
  // conv1: (16,12,128,128) -> out ch 0..47 of (16,96,256,256)
  convt_bn_relu_kernel<12, 12, 128, 128><<<dim3(8, 8, 96), blk, 0, stream>>>(
      xl1, w1, b1, g1, be1, m1, v1, out, 96, 0);
  // conv2a: (16,48,64,64) -> (16,48,128,128) scratch
  convt_bn_relu_kernel<48, 8, 64, 64><<<dim3(4, 4, 96), blk, 0, stream>>>(
      xl2, w2a, b2a, g2a, be2a, m2a, v2a, o2a, 48, 0);
  // conv2b: (16,48,128,128) -> out ch 48..95
  convt_bn_relu_kernel<48, 8, 128, 128><<<dim3(8, 8, 96), blk, 0, stream>>>(
      o2a, w2b, b2b, g2b, be2b, m2b, v2b, out, 96, 48);
}

// Round 3
// 196.544 us; speedup vs baseline: 2.7852x; 2.7852x over previous
//
#include <hip/hip_runtime.h>

typedef short s16x8 __attribute__((ext_vector_type(8)));
typedef float f32x4 __attribute__((ext_vector_type(4)));
typedef unsigned short u16;

#define BN_EPS 1e-5f

__device__ __forceinline__ u16 f2bf(float f) {
  union { float f; unsigned u; } v; v.f = f;
  unsigned r = (v.u + 0x7fffu + ((v.u >> 16) & 1u)) >> 16;
  return (u16)r;
}
__device__ __forceinline__ float bf2f(u16 u) {
  union { unsigned u; float f; } v; v.u = ((unsigned)u) << 16; return v.f;
}

// ---------------- DWT level from fp32 input -> bf16 out ---------------------
__global__ __launch_bounds__(256) void dwt_f32_kernel(
    const float* __restrict__ in, u16* __restrict__ out,
    int B, int C, int H, int W)
{
  int H2 = H >> 1, W2 = W >> 1;
  long total = (long)B * C * H2 * W2;
  long idx = (long)blockIdx.x * 256 + threadIdx.x;
  if (idx >= total) return;
  int w2 = (int)(idx % W2); long t = idx / W2;
  int h2 = (int)(t % H2); t /= H2;
  int c = (int)(t % C); int b = (int)(t / C);
  const float* p = in + (((long)(b * C + c) * H + 2 * h2) * W + 2 * w2);
  float2 u = *(const float2*)p;
  float2 v = *(const float2*)(p + W);
  float a = u.x, bb = u.y, cc = v.x, dd = v.y;
  float ll = (a + bb + cc + dd) * 0.5f;
  float lh = (a + bb - cc - dd) * 0.5f;
  float hl = (a - bb + cc - dd) * 0.5f;
  float hh = (a - bb - cc + dd) * 0.5f;
  long cs = (long)H2 * W2;
  u16* q = out + ((long)(b * 4 * C + 4 * c)) * cs + (long)h2 * W2 + w2;
  q[0] = f2bf(ll); q[cs] = f2bf(lh); q[2 * cs] = f2bf(hl); q[3 * cs] = f2bf(hh);
}

// ---------------- DWT level from bf16 input -> bf16 out ---------------------
__global__ __launch_bounds__(256) void dwt_bf16_kernel(
    const u16* __restrict__ in, u16* __restrict__ out,
    int B, int C, int H, int W)
{
  int H2 = H >> 1, W2 = W >> 1;
  long total = (long)B * C * H2 * W2;
  long idx = (long)blockIdx.x * 256 + threadIdx.x;
  if (idx >= total) return;
  int w2 = (int)(idx % W2); long t = idx / W2;
  int h2 = (int)(t % H2); t /= H2;
  int c = (int)(t % C); int b = (int)(t / C);
  const u16* p = in + (((long)(b * C + c) * H + 2 * h2) * W + 2 * w2);
  unsigned r0 = *(const unsigned*)p;
  unsigned r1 = *(const unsigned*)(p + W);
  float a = bf2f((u16)(r0 & 0xffff)), bb = bf2f((u16)(r0 >> 16));
  float cc = bf2f((u16)(r1 & 0xffff)), dd = bf2f((u16)(r1 >> 16));
  float ll = (a + bb + cc + dd) * 0.5f;
  float lh = (a + bb - cc - dd) * 0.5f;
  float hl = (a - bb + cc - dd) * 0.5f;
  float hh = (a - bb - cc + dd) * 0.5f;
  long cs = (long)H2 * W2;
  u16* q = out + ((long)(b * 4 * C + 4 * c)) * cs + (long)h2 * W2 + w2;
  q[0] = f2bf(ll); q[cs] = f2bf(lh); q[2 * cs] = f2bf(hl); q[3 * cs] = f2bf(hh);
}

// -------- setup: pack per-lane B fragments + BN (inv, shift) ---------------
// Bp layout: [p(4)][s(KSTEPS)][nt(3)][lane(64)][j(8)] bf16
// k = s*32 + (lane>>4)*8 + j ; tap = k/CIP ; ci = k%CIP
// kh = 2*ty + 1 - py ; kw = 2*tx + 1 - px ; value = w[ci][n][kh][kw]
__global__ __launch_bounds__(256) void setup_kernel(
    const float* __restrict__ w, const float* __restrict__ bias,
    const float* __restrict__ g, const float* __restrict__ be,
    const float* __restrict__ mu, const float* __restrict__ var,
    u16* __restrict__ Bp, float* __restrict__ bnp,
    int CIN, int CIP, int KSTEPS)
{
  int e = blockIdx.x * 256 + threadIdx.x;
  if (e < 48) {
    float iv = g[e] * rsqrtf(var[e] + BN_EPS);
    bnp[e] = iv;
    bnp[48 + e] = (bias[e] - mu[e]) * iv + be[e];
  }
  int total = 4 * KSTEPS * 1536;
  if (e >= total) return;
  int j = e & 7;
  int l = (e >> 3) & 63;
  int nt = (e >> 9) % 3;
  int sp = e / 1536;
  int s = sp % KSTEPS;
  int p = sp / KSTEPS;
  int py = p >> 1, px = p & 1;
  int n = nt * 16 + (l & 15);
  int k = s * 32 + (l >> 4) * 8 + j;
  int tap = k / CIP, ci = k % CIP;
  int kh = 2 * (tap >> 1) + 1 - py;
  int kw = 2 * (tap & 1) + 1 - px;
  float v = (ci < CIN) ? w[((ci * 48 + n) * 4 + kh) * 4 + kw] : 0.f;
  Bp[e] = f2bf(v);
}

// -------- ConvT(4,2,1)+BN+ReLU via MFMA implicit GEMM ----------------------
// Block: 16x16 input quads (32x32 output) x all 48 co. 4 waves = 4 parities.
// Per wave/parity GEMM: M=256 (qx within m-tile, qy = m-tile), N=48, K=4*CIP.
// mfma(Bfrag, Afrag, acc) -> D^T: row=co_local=4*(l>>4)+r, col=qx=l&15.
template<int CIN, int CIP, int HIN, int WIN, bool OBF16>
__global__ __launch_bounds__(256, 2) void convt_mfma(
    const u16* __restrict__ in,    // (B, CIN, HIN, WIN) bf16
    const u16* __restrict__ Bp,    // packed B fragments
    const float* __restrict__ bnp, // inv[48], sh[48]
    void* __restrict__ outv, int outc, int obase)
{
  constexpr int KSTEPS = CIP / 8;
  constexpr int IT = 18;
  constexpr int HOUT = 2 * HIN, WOUT = 2 * WIN;
  __shared__ __align__(16) u16 in_lds[IT * IT * CIP];

  const int tid = threadIdx.x;
  const int n = blockIdx.z;
  const int qY0 = blockIdx.y * 16;
  const int qX0 = blockIdx.x * 16;

  // ---- stage input tile [y][x][ci_rot] (bf16), zero halo + ci padding ----
  for (int i = tid; i < IT * IT * CIP; i += 256) {
    int ci = i / (IT * IT);
    int rem = i - ci * IT * IT;
    int y = rem / IT, x = rem - y * IT;
    int ih = qY0 - 1 + y, iw = qX0 - 1 + x;
    u16 v = 0;
    if ((CIP == CIN || ci < CIN) &&
        (unsigned)ih < (unsigned)HIN && (unsigned)iw < (unsigned)WIN)
      v = in[(((long)n * CIN + ci) * HIN + ih) * WIN + iw];
    int rot = 8 * ((x >> 2) & 3);       // {0,8,16,24}
    if (rot >= CIP) rot -= CIP;         // proper mod for CIP=16
    int cr = ci + rot;
    if (cr >= CIP) cr -= CIP;
    in_lds[(y * IT + x) * CIP + cr] = v;
  }

  const int wid = tid >> 6, lane = tid & 63;
  const int py = wid >> 1, px = wid & 1;
  const int g = lane >> 4, qx = lane & 15;

  // ---- B fragments (held in registers for the whole kernel) ----
  s16x8 bf[KSTEPS][3];
  const s16x8* bpp = (const s16x8*)Bp + (wid * KSTEPS * 3) * 64 + lane;
  #pragma unroll
  for (int s = 0; s < KSTEPS; ++s)
    #pragma unroll
    for (int nt = 0; nt < 3; ++nt)
      bf[s][nt] = bpp[(s * 3 + nt) * 64];

  // ---- BN params per lane: co = nt*16 + 4*g + r ----
  float4 inv4[3], sh4[3];
  #pragma unroll
  for (int nt = 0; nt < 3; ++nt) {
    inv4[nt] = *(const float4*)&bnp[nt * 16 + 4 * g];
    sh4[nt]  = *(const float4*)&bnp[48 + nt * 16 + 4 * g];
  }

  // ---- per-kstep A-read base (elements, qy=0 row) ----
  int abase[KSTEPS];
  #pragma unroll
  for (int s = 0; s < KSTEPS; ++s) {
    int k0 = s * 32 + g * 8;
    int tap = k0 / CIP, ci0 = k0 - tap * CIP;
    int ty = tap >> 1, tx = tap & 1;
    int y = 1 + py - ty;
    int x = qx + 1 + px - tx;
    int rot = 8 * ((x >> 2) & 3);
    if (rot >= CIP) rot -= CIP;
    int cr = ci0 + rot;
    if (cr >= CIP) cr -= CIP;
    abase[s] = (y * IT + x) * CIP + cr;
  }

  __syncthreads();

  const int ow = 2 * (qX0 + qx) + px;
  for (int mc = 0; mc < 4; ++mc) {
    f32x4 acc[4][3];
    #pragma unroll
    for (int mt = 0; mt < 4; ++mt)
      #pragma unroll
      for (int nt = 0; nt < 3; ++nt)
        acc[mt][nt] = f32x4{0.f, 0.f, 0.f, 0.f};

    #pragma unroll
    for (int s = 0; s < KSTEPS; ++s) {
      #pragma unroll
      for (int mt = 0; mt < 4; ++mt) {
        const int qy = mc * 4 + mt;
        s16x8 a = *(const s16x8*)&in_lds[abase[s] + qy * (IT * CIP)];
        #pragma unroll
        for (int nt = 0; nt < 3; ++nt)
          acc[mt][nt] = __builtin_amdgcn_mfma_f32_16x16x32_bf16(
              bf[s][nt], a, acc[mt][nt], 0, 0, 0);
      }
    }

    // ---- epilogue: BN+ReLU, store (D^T: row co_local = 4g+r, col qx) ----
    #pragma unroll
    for (int mt = 0; mt < 4; ++mt) {
      const int oh = 2 * (qY0 + mc * 4 + mt) + py;
      #pragma unroll
      for (int nt = 0; nt < 3; ++nt) {
        const float iv[4] = {inv4[nt].x, inv4[nt].y, inv4[nt].z, inv4[nt].w};
        const float sv[4] = {sh4[nt].x, sh4[nt].y, sh4[nt].z, sh4[nt].w};
        #pragma unroll
        for (int r = 0; r < 4; ++r) {
          const int co = obase + nt * 16 + 4 * g + r;
          float v = fmaxf(acc[mt][nt][r] * iv[r] + sv[r], 0.f);
          int off = ((n * outc + co) * HOUT + oh) * WOUT + ow;
          if (OBF16) ((u16*)outv)[off] = f2bf(v);
          else       ((float*)outv)[off] = v;
        }
      }
    }
  }
}

extern "C" void kernel_launch(void* const* d_in, const int* in_sizes, int n_in,
                              void* d_out, int out_size, void* d_ws, size_t ws_size,
                              hipStream_t stream) {
  const float* x    = (const float*)d_in[0];
  const float* w1   = (const float*)d_in[1];
  const float* b1   = (const float*)d_in[2];
  const float* g1   = (const float*)d_in[3];
  const float* be1  = (const float*)d_in[4];
  const float* m1   = (const float*)d_in[5];
  const float* v1   = (const float*)d_in[6];
  const float* w2a  = (const float*)d_in[7];
  const float* b2a  = (const float*)d_in[8];
  const float* g2a  = (const float*)d_in[9];
  const float* be2a = (const float*)d_in[10];
  const float* m2a  = (const float*)d_in[11];
  const float* v2a  = (const float*)d_in[12];
  const float* w2b  = (const float*)d_in[13];
  const float* b2b  = (const float*)d_in[14];
  const float* g2b  = (const float*)d_in[15];
  const float* be2b = (const float*)d_in[16];
  const float* m2b  = (const float*)d_in[17];
  const float* v2b  = (const float*)d_in[18];

  float* out = (float*)d_out;
  char* ws = (char*)d_ws;
  u16* xl1  = (u16*)ws;                         // 16*12*128*128*2 = 6291456
  u16* xl2  = (u16*)(ws + 6291456);             // 16*48*64*64*2   = 6291456
  u16* o2a  = (u16*)(ws + 12582912);            // 16*48*128*128*2 = 25165824
  u16* Bp1  = (u16*)(ws + 37748736);            // 12288*2
  u16* Bp2a = (u16*)(ws + 37773312);            // 36864*2
  u16* Bp2b = (u16*)(ws + 37847040);            // 36864*2
  float* bnp1  = (float*)(ws + 37920768);
  float* bnp2a = (float*)(ws + 37921152);
  float* bnp2b = (float*)(ws + 37921536);

  // setup: pack weights + BN params
  setup_kernel<<<48, 256, 0, stream>>>(w1, b1, g1, be1, m1, v1, Bp1, bnp1, 12, 16, 2);
  setup_kernel<<<144, 256, 0, stream>>>(w2a, b2a, g2a, be2a, m2a, v2a, Bp2a, bnp2a, 48, 48, 6);
  setup_kernel<<<144, 256, 0, stream>>>(w2b, b2b, g2b, be2b, m2b, v2b, Bp2b, bnp2b, 48, 48, 6);

  // DWT level 1 (fp32 -> bf16) and level 2 (bf16 -> bf16)
  dwt_f32_kernel<<<3072, 256, 0, stream>>>(x, xl1, 16, 3, 256, 256);
  dwt_bf16_kernel<<<3072, 256, 0, stream>>>(xl1, xl2, 16, 12, 128, 128);

  // conv1: (16,12,128,128) -> out ch 0..47 (fp32)
  convt_mfma<12, 16, 128, 128, false><<<dim3(8, 8, 16), 256, 0, stream>>>(
      xl1, Bp1, bnp1, out, 96, 0);
  // conv2a: (16,48,64,64) -> o2a (bf16)
  convt_mfma<48, 48, 64, 64, true><<<dim3(4, 4, 16), 256, 0, stream>>>(
      xl2, Bp2a, bnp2a, o2a, 48, 0);
  // conv2b: (16,48,128,128) -> out ch 48..95 (fp32)
  convt_mfma<48, 48, 128, 128, false><<<dim3(8, 8, 16), 256, 0, stream>>>(
      o2a, Bp2b, bnp2b, out, 96, 48);
}

// Round 4
// 138.665 us; speedup vs baseline: 3.9478x; 1.4174x over previous
//
#include <hip/hip_runtime.h>

typedef short s16x8 __attribute__((ext_vector_type(8)));
typedef float f32x4 __attribute__((ext_vector_type(4)));
typedef unsigned short u16;

#define BN_EPS 1e-5f

__device__ __forceinline__ u16 f2bf(float f) {
  union { float f; unsigned u; } v; v.f = f;
  unsigned r = (v.u + 0x7fffu + ((v.u >> 16) & 1u)) >> 16;
  return (u16)r;
}
__device__ __forceinline__ float bf2f(u16 u) {
  union { unsigned u; float f; } v; v.u = ((unsigned)u) << 16; return v.f;
}

// ---------------- DWT level from fp32 input -> bf16 out ---------------------
__global__ __launch_bounds__(256) void dwt_f32_kernel(
    const float* __restrict__ in, u16* __restrict__ out,
    int B, int C, int H, int W)
{
  int H2 = H >> 1, W2 = W >> 1;
  long total = (long)B * C * H2 * W2;
  long idx = (long)blockIdx.x * 256 + threadIdx.x;
  if (idx >= total) return;
  int w2 = (int)(idx % W2); long t = idx / W2;
  int h2 = (int)(t % H2); t /= H2;
  int c = (int)(t % C); int b = (int)(t / C);
  const float* p = in + (((long)(b * C + c) * H + 2 * h2) * W + 2 * w2);
  float2 u = *(const float2*)p;
  float2 v = *(const float2*)(p + W);
  float a = u.x, bb = u.y, cc = v.x, dd = v.y;
  float ll = (a + bb + cc + dd) * 0.5f;
  float lh = (a + bb - cc - dd) * 0.5f;
  float hl = (a - bb + cc - dd) * 0.5f;
  float hh = (a - bb - cc + dd) * 0.5f;
  long cs = (long)H2 * W2;
  u16* q = out + ((long)(b * 4 * C + 4 * c)) * cs + (long)h2 * W2 + w2;
  q[0] = f2bf(ll); q[cs] = f2bf(lh); q[2 * cs] = f2bf(hl); q[3 * cs] = f2bf(hh);
}

// ---------------- DWT level from bf16 input -> bf16 out ---------------------
__global__ __launch_bounds__(256) void dwt_bf16_kernel(
    const u16* __restrict__ in, u16* __restrict__ out,
    int B, int C, int H, int W)
{
  int H2 = H >> 1, W2 = W >> 1;
  long total = (long)B * C * H2 * W2;
  long idx = (long)blockIdx.x * 256 + threadIdx.x;
  if (idx >= total) return;
  int w2 = (int)(idx % W2); long t = idx / W2;
  int h2 = (int)(t % H2); t /= H2;
  int c = (int)(t % C); int b = (int)(t / C);
  const u16* p = in + (((long)(b * C + c) * H + 2 * h2) * W + 2 * w2);
  unsigned r0 = *(const unsigned*)p;
  unsigned r1 = *(const unsigned*)(p + W);
  float a = bf2f((u16)(r0 & 0xffff)), bb = bf2f((u16)(r0 >> 16));
  float cc = bf2f((u16)(r1 & 0xffff)), dd = bf2f((u16)(r1 >> 16));
  float ll = (a + bb + cc + dd) * 0.5f;
  float lh = (a + bb - cc - dd) * 0.5f;
  float hl = (a - bb + cc - dd) * 0.5f;
  float hh = (a - bb - cc + dd) * 0.5f;
  long cs = (long)H2 * W2;
  u16* q = out + ((long)(b * 4 * C + 4 * c)) * cs + (long)h2 * W2 + w2;
  q[0] = f2bf(ll); q[cs] = f2bf(lh); q[2 * cs] = f2bf(hl); q[3 * cs] = f2bf(hh);
}

// -------- setup: pack per-lane B fragments + BN (inv, shift) ---------------
__global__ __launch_bounds__(256) void setup_kernel(
    const float* __restrict__ w, const float* __restrict__ bias,
    const float* __restrict__ g, const float* __restrict__ be,
    const float* __restrict__ mu, const float* __restrict__ var,
    u16* __restrict__ Bp, float* __restrict__ bnp,
    int CIN, int CIP, int KSTEPS)
{
  int e = blockIdx.x * 256 + threadIdx.x;
  if (e < 48) {
    float iv = g[e] * rsqrtf(var[e] + BN_EPS);
    bnp[e] = iv;
    bnp[48 + e] = (bias[e] - mu[e]) * iv + be[e];
  }
  int total = 4 * KSTEPS * 1536;
  if (e >= total) return;
  int j = e & 7;
  int l = (e >> 3) & 63;
  int nt = (e >> 9) % 3;
  int sp = e / 1536;
  int s = sp % KSTEPS;
  int p = sp / KSTEPS;
  int py = p >> 1, px = p & 1;
  int n = nt * 16 + (l & 15);
  int k = s * 32 + (l >> 4) * 8 + j;
  int tap = k / CIP, ci = k % CIP;
  int kh = 2 * (tap >> 1) + 1 - py;
  int kw = 2 * (tap & 1) + 1 - px;
  float v = (ci < CIN) ? w[((ci * 48 + n) * 4 + kh) * 4 + kw] : 0.f;
  Bp[e] = f2bf(v);
}

// -------- ConvT(4,2,1)+BN+ReLU via MFMA implicit GEMM ----------------------
// Block: 16x16 input quads (32x32 output) x all 48 co. 4 waves = 4 parities.
// Epilogue: per 2-qy-row chunk, transpose through LDS -> contiguous float4.
template<int CIN, int CIP, int HIN, int WIN, bool OBF16>
__global__ __launch_bounds__(256, 2) void convt_mfma(
    const u16* __restrict__ in,    // (B, CIN, HIN, WIN) bf16
    const u16* __restrict__ Bp,    // packed B fragments
    const float* __restrict__ bnp, // inv[48], sh[48]
    void* __restrict__ outv, int outc, int obase)
{
  constexpr int KSTEPS = CIP / 8;
  constexpr int IT = 18;
  constexpr int HOUT = 2 * HIN, WOUT = 2 * WIN;
  __shared__ __align__(16) u16 in_lds[IT * IT * CIP];
  __shared__ __align__(16) float out_lds[48 * 4 * 32];  // [co][ohl][owl]

  const int tid = threadIdx.x;
  const int n = blockIdx.z;
  const int qY0 = blockIdx.y * 16;
  const int qX0 = blockIdx.x * 16;

  // ---- stage input tile [y][x][ci_rot], vectorized 16B loads -------------
  // task t = (ci*18 + y)*2 + half ; half covers x = 1+8*half .. 8+8*half
  // plus halo elem x = 0 (half 0) / x = 17 (half 1)
  {
    constexpr int NTASK = CIP * IT * 2;
    for (int t = tid; t < NTASK; t += 256) {
      int half = t & 1;
      int rowid = t >> 1;
      int ci = rowid / IT;
      int y = rowid - ci * IT;
      int ih = qY0 - 1 + y;
      bool rowok = (CIP == CIN || ci < CIN) && ((unsigned)ih < (unsigned)HIN);
      const u16* gsrc = in + (((long)n * CIN + ci) * HIN + ih) * WIN + qX0 + 8 * half;
      s16x8 v = {0, 0, 0, 0, 0, 0, 0, 0};
      if (rowok) v = *(const s16x8*)gsrc;
      int xh = half ? 17 : 0;
      int iwh = qX0 - 1 + xh;
      u16 hv = 0;
      if (rowok && (unsigned)iwh < (unsigned)WIN) hv = gsrc[half ? 8 : -1];
      int base_yx = y * IT;
      #pragma unroll
      for (int j = 0; j < 8; ++j) {
        int x = 1 + 8 * half + j;
        int rot = 8 * ((x >> 2) & 3);
        if (rot >= CIP) rot -= CIP;
        int cr = ci + rot;
        if (cr >= CIP) cr -= CIP;
        in_lds[(base_yx + x) * CIP + cr] = (u16)v[j];
      }
      {
        int rot = 8 * ((xh >> 2) & 3);
        if (rot >= CIP) rot -= CIP;
        int cr = ci + rot;
        if (cr >= CIP) cr -= CIP;
        in_lds[(base_yx + xh) * CIP + cr] = hv;
      }
    }
  }

  const int wid = tid >> 6, lane = tid & 63;
  const int py = wid >> 1, px = wid & 1;
  const int g = lane >> 4, qx = lane & 15;

  // ---- B fragments (registers for whole kernel) ----
  s16x8 bf[KSTEPS][3];
  const s16x8* bpp = (const s16x8*)Bp + (wid * KSTEPS * 3) * 64 + lane;
  #pragma unroll
  for (int s = 0; s < KSTEPS; ++s)
    #pragma unroll
    for (int nt = 0; nt < 3; ++nt)
      bf[s][nt] = bpp[(s * 3 + nt) * 64];

  // ---- BN params per lane: co = nt*16 + 4*g + r ----
  float4 inv4[3], sh4[3];
  #pragma unroll
  for (int nt = 0; nt < 3; ++nt) {
    inv4[nt] = *(const float4*)&bnp[nt * 16 + 4 * g];
    sh4[nt]  = *(const float4*)&bnp[48 + nt * 16 + 4 * g];
  }

  // ---- per-kstep A-read base ----
  int abase[KSTEPS];
  #pragma unroll
  for (int s = 0; s < KSTEPS; ++s) {
    int k0 = s * 32 + g * 8;
    int tap = k0 / CIP, ci0 = k0 - tap * CIP;
    int ty = tap >> 1, tx = tap & 1;
    int y = 1 + py - ty;
    int x = qx + 1 + px - tx;
    int rot = 8 * ((x >> 2) & 3);
    if (rot >= CIP) rot -= CIP;
    int cr = ci0 + rot;
    if (cr >= CIP) cr -= CIP;
    abase[s] = (y * IT + x) * CIP + cr;
  }

  __syncthreads();

  for (int mc = 0; mc < 4; ++mc) {
    f32x4 acc[4][3];
    #pragma unroll
    for (int mt = 0; mt < 4; ++mt)
      #pragma unroll
      for (int nt = 0; nt < 3; ++nt)
        acc[mt][nt] = f32x4{0.f, 0.f, 0.f, 0.f};

    #pragma unroll
    for (int s = 0; s < KSTEPS; ++s) {
      #pragma unroll
      for (int mt = 0; mt < 4; ++mt) {
        const int qy = mc * 4 + mt;
        s16x8 a = *(const s16x8*)&in_lds[abase[s] + qy * (IT * CIP)];
        #pragma unroll
        for (int nt = 0; nt < 3; ++nt)
          acc[mt][nt] = __builtin_amdgcn_mfma_f32_16x16x32_bf16(
              bf[s][nt], a, acc[mt][nt], 0, 0, 0);
      }
    }

    // ---- epilogue: BN+ReLU -> LDS transpose -> contiguous wide stores ----
    #pragma unroll
    for (int c2 = 0; c2 < 2; ++c2) {
      __syncthreads();   // out_lds free (prev chunk's reads done)
      #pragma unroll
      for (int mtl = 0; mtl < 2; ++mtl) {
        const int mt = 2 * c2 + mtl;
        const int ohl = 2 * mtl + py;
        #pragma unroll
        for (int nt = 0; nt < 3; ++nt) {
          #pragma unroll
          for (int r = 0; r < 4; ++r) {
            const int co_l = nt * 16 + 4 * g + r;
            float iv = ((const float*)&inv4[nt])[r];
            float sv = ((const float*)&sh4[nt])[r];
            float val = fmaxf(acc[mt][nt][r] * iv + sv, 0.f);
            out_lds[(co_l * 4 + ohl) * 32 + 2 * qx + px] = val;
          }
        }
      }
      __syncthreads();   // out_lds filled
      const int oh_base = 2 * (qY0 + 4 * mc + 2 * c2);
      #pragma unroll
      for (int u = 0; u < 6; ++u) {
        int e = u * 256 + tid;
        int owq = e & 7, ohl = (e >> 3) & 3, co_l = e >> 5;
        float4 vv = *(const float4*)&out_lds[(co_l * 4 + ohl) * 32 + 4 * owq];
        long off = (((long)(n * outc + obase + co_l) * HOUT + oh_base + ohl) * WOUT)
                   + 2 * qX0 + 4 * owq;
        if (OBF16) {
          u16 h0 = f2bf(vv.x), h1 = f2bf(vv.y), h2 = f2bf(vv.z), h3 = f2bf(vv.w);
          unsigned lo = (unsigned)h0 | ((unsigned)h1 << 16);
          unsigned hi = (unsigned)h2 | ((unsigned)h3 << 16);
          uint2 pk; pk.x = lo; pk.y = hi;
          *(uint2*)((u16*)outv + off) = pk;
        } else {
          *(float4*)((float*)outv + off) = vv;
        }
      }
    }
  }
}

extern "C" void kernel_launch(void* const* d_in, const int* in_sizes, int n_in,
                              void* d_out, int out_size, void* d_ws, size_t ws_size,
                              hipStream_t stream) {
  const float* x    = (const float*)d_in[0];
  const float* w1   = (const float*)d_in[1];
  const float* b1   = (const float*)d_in[2];
  const float* g1   = (const float*)d_in[3];
  const float* be1  = (const float*)d_in[4];
  const float* m1   = (const float*)d_in[5];
  const float* v1   = (const float*)d_in[6];
  const float* w2a  = (const float*)d_in[7];
  const float* b2a  = (const float*)d_in[8];
  const float* g2a  = (const float*)d_in[9];
  const float* be2a = (const float*)d_in[10];
  const float* m2a  = (const float*)d_in[11];
  const float* v2a  = (const float*)d_in[12];
  const float* w2b  = (const float*)d_in[13];
  const float* b2b  = (const float*)d_in[14];
  const float* g2b  = (const float*)d_in[15];
  const float* be2b = (const float*)d_in[16];
  const float* m2b  = (const float*)d_in[17];
  const float* v2b  = (const float*)d_in[18];

  float* out = (float*)d_out;
  char* ws = (char*)d_ws;
  u16* xl1  = (u16*)ws;                         // 16*12*128*128*2 = 6291456
  u16* xl2  = (u16*)(ws + 6291456);             // 16*48*64*64*2   = 6291456
  u16* o2a  = (u16*)(ws + 12582912);            // 16*48*128*128*2 = 25165824
  u16* Bp1  = (u16*)(ws + 37748736);
  u16* Bp2a = (u16*)(ws + 37773312);
  u16* Bp2b = (u16*)(ws + 37847040);
  float* bnp1  = (float*)(ws + 37920768);
  float* bnp2a = (float*)(ws + 37921152);
  float* bnp2b = (float*)(ws + 37921536);

  // setup: pack weights + BN params
  setup_kernel<<<48, 256, 0, stream>>>(w1, b1, g1, be1, m1, v1, Bp1, bnp1, 12, 16, 2);
  setup_kernel<<<144, 256, 0, stream>>>(w2a, b2a, g2a, be2a, m2a, v2a, Bp2a, bnp2a, 48, 48, 6);
  setup_kernel<<<144, 256, 0, stream>>>(w2b, b2b, g2b, be2b, m2b, v2b, Bp2b, bnp2b, 48, 48, 6);

  // DWT level 1 (fp32 -> bf16) and level 2 (bf16 -> bf16)
  dwt_f32_kernel<<<3072, 256, 0, stream>>>(x, xl1, 16, 3, 256, 256);
  dwt_bf16_kernel<<<3072, 256, 0, stream>>>(xl1, xl2, 16, 12, 128, 128);

  // conv1: (16,12,128,128) -> out ch 0..47 (fp32)
  convt_mfma<12, 16, 128, 128, false><<<dim3(8, 8, 16), 256, 0, stream>>>(
      xl1, Bp1, bnp1, out, 96, 0);
  // conv2a: (16,48,64,64) -> o2a (bf16)
  convt_mfma<48, 48, 64, 64, true><<<dim3(4, 4, 16), 256, 0, stream>>>(
      xl2, Bp2a, bnp2a, o2a, 48, 0);
  // conv2b: (16,48,128,128) -> out ch 48..95 (fp32)
  convt_mfma<48, 48, 128, 128, false><<<dim3(8, 8, 16), 256, 0, stream>>>(
      o2a, Bp2b, bnp2b, out, 96, 48);
}

// Round 7
// 130.915 us; speedup vs baseline: 4.1815x; 1.0592x over previous
//
#include <hip/hip_runtime.h>

typedef short s16x8 __attribute__((ext_vector_type(8)));
typedef float f32x4 __attribute__((ext_vector_type(4)));
typedef unsigned short u16;

#define BN_EPS 1e-5f

__device__ __forceinline__ u16 f2bf(float f) {
  union { float f; unsigned u; } v; v.f = f;
  unsigned r = (v.u + 0x7fffu + ((v.u >> 16) & 1u)) >> 16;
  return (u16)r;
}
__device__ __forceinline__ float bf2f(u16 u) {
  union { unsigned u; float f; } v; v.u = ((unsigned)u) << 16; return v.f;
}

// -------- fused DWT level1+level2: x(f32) -> xl1(bf16), xl2(bf16) ----------
__global__ __launch_bounds__(256) void dwt_fused_kernel(
    const float* __restrict__ x, u16* __restrict__ xl1, u16* __restrict__ xl2)
{
  int idx = blockIdx.x * 256 + threadIdx.x;   // 16*3*64*64 = 196608
  int w4 = idx & 63; int t = idx >> 6;
  int h4 = t & 63; t >>= 6;
  int c = t % 3; int b = t / 3;
  const float* p = x + (((long)(b * 3 + c) * 256 + 4 * h4) * 256 + 4 * w4);
  float4 r[4];
  r[0] = *(const float4*)p;
  r[1] = *(const float4*)(p + 256);
  r[2] = *(const float4*)(p + 512);
  r[3] = *(const float4*)(p + 768);
  float rows[4][4] = {{r[0].x, r[0].y, r[0].z, r[0].w},
                      {r[1].x, r[1].y, r[1].z, r[1].w},
                      {r[2].x, r[2].y, r[2].z, r[2].w},
                      {r[3].x, r[3].y, r[3].z, r[3].w}};
  float sb[4][2][2];
  #pragma unroll
  for (int qy = 0; qy < 2; ++qy)
    #pragma unroll
    for (int qx = 0; qx < 2; ++qx) {
      float a = rows[2 * qy][2 * qx],     bb = rows[2 * qy][2 * qx + 1];
      float cc = rows[2 * qy + 1][2 * qx], dd = rows[2 * qy + 1][2 * qx + 1];
      sb[0][qy][qx] = (a + bb + cc + dd) * 0.5f;
      sb[1][qy][qx] = (a + bb - cc - dd) * 0.5f;
      sb[2][qy][qx] = (a - bb + cc - dd) * 0.5f;
      sb[3][qy][qx] = (a - bb - cc + dd) * 0.5f;
    }
  // xl1 (B,12,128,128): channel 4c+s
  #pragma unroll
  for (int s = 0; s < 4; ++s)
    #pragma unroll
    for (int qy = 0; qy < 2; ++qy) {
      unsigned pk = (unsigned)f2bf(sb[s][qy][0]) | ((unsigned)f2bf(sb[s][qy][1]) << 16);
      *(unsigned*)&xl1[(((long)(b * 12 + 4 * c + s) * 128) + 2 * h4 + qy) * 128 + 2 * w4] = pk;
    }
  // xl2 (B,48,64,64): channel (4c+s)*4 + s2
  #pragma unroll
  for (int s = 0; s < 4; ++s) {
    float a = sb[s][0][0], bb = sb[s][0][1], cc = sb[s][1][0], dd = sb[s][1][1];
    float o[4] = {(a + bb + cc + dd) * 0.5f, (a + bb - cc - dd) * 0.5f,
                  (a - bb + cc - dd) * 0.5f, (a - bb - cc + dd) * 0.5f};
    #pragma unroll
    for (int s2 = 0; s2 < 4; ++s2)
      xl2[(((long)(b * 48 + (4 * c + s) * 4 + s2) * 64) + h4) * 64 + w4] = f2bf(o[s2]);
  }
}

// -------- setup: pack per-lane B fragments + BN, all 3 convs in one --------
__device__ void setup_one(
    const float* __restrict__ w, const float* __restrict__ bias,
    const float* __restrict__ g, const float* __restrict__ be,
    const float* __restrict__ mu, const float* __restrict__ var,
    u16* __restrict__ Bp, float* __restrict__ bnp,
    int CIN, int CIP, int KSTEPS, int e)
{
  if (e < 48) {
    float iv = g[e] * rsqrtf(var[e] + BN_EPS);
    bnp[e] = iv;
    bnp[48 + e] = (bias[e] - mu[e]) * iv + be[e];
  }
  int total = 4 * KSTEPS * 1536;
  if (e >= total) return;
  int j = e & 7;
  int l = (e >> 3) & 63;
  int nt = (e >> 9) % 3;
  int sp = e / 1536;
  int s = sp % KSTEPS;
  int p = sp / KSTEPS;
  int py = p >> 1, px = p & 1;
  int n = nt * 16 + (l & 15);
  int k = s * 32 + (l >> 4) * 8 + j;
  int tap = k / CIP, ci = k % CIP;
  int kh = 2 * (tap >> 1) + 1 - py;
  int kw = 2 * (tap & 1) + 1 - px;
  float v = (ci < CIN) ? w[((ci * 48 + n) * 4 + kh) * 4 + kw] : 0.f;
  Bp[e] = f2bf(v);
}

__global__ __launch_bounds__(256) void setup_all_kernel(
    const float* w1, const float* b1, const float* g1, const float* be1,
    const float* m1, const float* v1, u16* Bp1, float* bnp1,
    const float* w2a, const float* b2a, const float* g2a, const float* be2a,
    const float* m2a, const float* v2a, u16* Bp2a, float* bnp2a,
    const float* w2b, const float* b2b, const float* g2b, const float* be2b,
    const float* m2b, const float* v2b, u16* Bp2b, float* bnp2b)
{
  int e = blockIdx.x * 256 + threadIdx.x;
  if (blockIdx.y == 0)      setup_one(w1, b1, g1, be1, m1, v1, Bp1, bnp1, 12, 16, 2, e);
  else if (blockIdx.y == 1) setup_one(w2a, b2a, g2a, be2a, m2a, v2a, Bp2a, bnp2a, 48, 48, 6, e);
  else                      setup_one(w2b, b2b, g2b, be2b, m2b, v2b, Bp2b, bnp2b, 48, 48, 6, e);
}

// -------- ConvT(4,2,1)+BN+ReLU via MFMA implicit GEMM ----------------------
// Block: 64x4 input quads (128x8 output) x all 48 co. 4 waves = 4 parities.
template<int CIN, int CIP, int HIN, int WIN, bool OBF16>
__global__ __launch_bounds__(256, 2) void convt_mfma(
    const u16* __restrict__ in,    // (B, CIN, HIN, WIN) bf16
    const u16* __restrict__ Bp,    // packed B fragments
    const float* __restrict__ bnp, // inv[48], sh[48]
    void* __restrict__ outv, int outc, int obase)
{
  constexpr int KSTEPS = CIP / 8;
  constexpr int ITX = 66, ITY = 6;
  constexpr int HOUT = 2 * HIN, WOUT = 2 * WIN;
  __shared__ __align__(16) u16 in_lds[ITX * ITY * CIP];
  __shared__ __align__(16) float out_lds[32 * 2 * 128];

  const int tid = threadIdx.x;
  const int n = blockIdx.z;
  const int qY0 = blockIdx.y * 4;
  const int qX0 = blockIdx.x * 64;

  // ---- stage input tile [y][x][ci_rot], 16B loads + halo ----
  {
    constexpr int NTASK = CIP * ITY * 8;
    for (int t = tid; t < NTASK; t += 256) {
      int seg = t & 7;
      int rowid = t >> 3;
      int ci = rowid / ITY;
      int y = rowid - ci * ITY;
      int ih = qY0 - 1 + y;
      bool rowok = (CIP == CIN || ci < CIN) && ((unsigned)ih < (unsigned)HIN);
      const u16* gsrc = in + (((long)n * CIN + ci) * HIN + ih) * WIN + qX0 + 8 * seg;
      s16x8 v = {0, 0, 0, 0, 0, 0, 0, 0};
      if (rowok) v = *(const s16x8*)gsrc;
      int base_yx = y * ITX;
      #pragma unroll
      for (int j = 0; j < 8; ++j) {
        int xx = 1 + 8 * seg + j;
        int rot = 8 * ((xx >> 2) & 3);
        if (rot >= CIP) rot -= CIP;
        int cr = ci + rot;
        if (cr >= CIP) cr -= CIP;
        in_lds[(base_yx + xx) * CIP + cr] = (u16)v[j];
      }
      if (seg == 0 || seg == 7) {
        int xh = (seg == 0) ? 0 : 65;
        int iwh = qX0 - 1 + xh;
        u16 hv = 0;
        if (rowok && (unsigned)iwh < (unsigned)WIN) hv = gsrc[(seg == 0) ? -1 : 8];
        int rot = 8 * ((xh >> 2) & 3);
        if (rot >= CIP) rot -= CIP;
        int cr = ci + rot;
        if (cr >= CIP) cr -= CIP;
        in_lds[(base_yx + xh) * CIP + cr] = hv;
      }
    }
  }

  const int wid = tid >> 6, lane = tid & 63;
  const int py = wid >> 1, px = wid & 1;
  const int g = lane >> 4, qx = lane & 15;

  // ---- B fragments (registers for whole kernel) ----
  s16x8 bf[KSTEPS][3];
  const s16x8* bpp = (const s16x8*)Bp + (wid * KSTEPS * 3) * 64 + lane;
  #pragma unroll
  for (int s = 0; s < KSTEPS; ++s)
    #pragma unroll
    for (int nt = 0; nt < 3; ++nt)
      bf[s][nt] = bpp[(s * 3 + nt) * 64];

  // ---- BN params per lane: co = nt*16 + 4*g + r ----
  float4 inv4[3], sh4[3];
  #pragma unroll
  for (int nt = 0; nt < 3; ++nt) {
    inv4[nt] = *(const float4*)&bnp[nt * 16 + 4 * g];
    sh4[nt]  = *(const float4*)&bnp[48 + nt * 16 + 4 * g];
  }

  // ---- per-kstep A-read base (mc=0, mt=0) ----
  int abase[KSTEPS];
  #pragma unroll
  for (int s = 0; s < KSTEPS; ++s) {
    int k0 = s * 32 + g * 8;
    int tap = k0 / CIP, ci0 = k0 - tap * CIP;
    int ty = tap >> 1, tx = tap & 1;
    int y = 1 + py - ty;
    int xx = qx + 1 + px - tx;
    int rot = 8 * ((xx >> 2) & 3);
    if (rot >= CIP) rot -= CIP;
    int cr = ci0 + rot;
    if (cr >= CIP) cr -= CIP;
    abase[s] = (y * ITX + xx) * CIP + cr;
  }

  __syncthreads();

  for (int mc = 0; mc < 4; ++mc) {
    f32x4 acc[4][3];
    #pragma unroll
    for (int mt = 0; mt < 4; ++mt)
      #pragma unroll
      for (int nt = 0; nt < 3; ++nt)
        acc[mt][nt] = f32x4{0.f, 0.f, 0.f, 0.f};

    #pragma unroll
    for (int s = 0; s < KSTEPS; ++s) {
      #pragma unroll
      for (int mt = 0; mt < 4; ++mt) {
        s16x8 a = *(const s16x8*)&in_lds[abase[s] + (mc * ITX + mt * 16) * CIP];
        #pragma unroll
        for (int nt = 0; nt < 3; ++nt)
          acc[mt][nt] = __builtin_amdgcn_mfma_f32_16x16x32_bf16(
              bf[s][nt], a, acc[mt][nt], 0, 0, 0);
      }
    }

    // ---- epilogue: two co-subchunks: {nt 0,1 -> 32 co}, {nt 2 -> 16 co} --
    #pragma unroll
    for (int sc = 0; sc < 2; ++sc) {
      const int ntlo = (sc == 0) ? 0 : 2;
      const int ntn  = (sc == 0) ? 2 : 1;
      const int coBase = ntlo * 16;
      __syncthreads();   // out_lds free
      #pragma unroll
      for (int ntl = 0; ntl < 2; ++ntl) {
        if (ntl < ntn) {
          const int nt = ntlo + ntl;
          #pragma unroll
          for (int mt = 0; mt < 4; ++mt) {
            #pragma unroll
            for (int r = 0; r < 4; ++r) {
              const int co_rel = ntl * 16 + 4 * g + r;
              float iv = ((const float*)&inv4[nt])[r];
              float sv = ((const float*)&sh4[nt])[r];
              float val = fmaxf(acc[mt][nt][r] * iv + sv, 0.f);
              out_lds[(co_rel * 2 + py) * 128 + 2 * (mt * 16 + qx) + px] = val;
            }
          }
        }
      }
      __syncthreads();   // out_lds filled
      // float4 elements: ntn*16 co * 2 parities * 32 per row = ntn*1024
      const int nIter = ntn * 4;
      #pragma unroll
      for (int u = 0; u < 8; ++u) {
        if (u < nIter) {
          int e = u * 256 + tid;
          int ow4 = e & 31, row = e >> 5;
          int co_l = coBase + (row >> 1), ohp = row & 1;
          f32x4 vv = *(const f32x4*)&out_lds[row * 128 + 4 * ow4];
          long off = (((long)(n * outc + obase + co_l) * HOUT + 2 * (qY0 + mc) + ohp) * WOUT)
                     + 2 * qX0 + 4 * ow4;
          if (OBF16) {
            unsigned lo = (unsigned)f2bf(vv.x) | ((unsigned)f2bf(vv.y) << 16);
            unsigned hi = (unsigned)f2bf(vv.z) | ((unsigned)f2bf(vv.w) << 16);
            uint2 pk; pk.x = lo; pk.y = hi;
            *(uint2*)((u16*)outv + off) = pk;
          } else {
            __builtin_nontemporal_store(vv, (f32x4*)((float*)outv + off));
          }
        }
      }
    }
  }
}

extern "C" void kernel_launch(void* const* d_in, const int* in_sizes, int n_in,
                              void* d_out, int out_size, void* d_ws, size_t ws_size,
                              hipStream_t stream) {
  const float* x    = (const float*)d_in[0];
  const float* w1   = (const float*)d_in[1];
  const float* b1   = (const float*)d_in[2];
  const float* g1   = (const float*)d_in[3];
  const float* be1  = (const float*)d_in[4];
  const float* m1   = (const float*)d_in[5];
  const float* v1   = (const float*)d_in[6];
  const float* w2a  = (const float*)d_in[7];
  const float* b2a  = (const float*)d_in[8];
  const float* g2a  = (const float*)d_in[9];
  const float* be2a = (const float*)d_in[10];
  const float* m2a  = (const float*)d_in[11];
  const float* v2a  = (const float*)d_in[12];
  const float* w2b  = (const float*)d_in[13];
  const float* b2b  = (const float*)d_in[14];
  const float* g2b  = (const float*)d_in[15];
  const float* be2b = (const float*)d_in[16];
  const float* m2b  = (const float*)d_in[17];
  const float* v2b  = (const float*)d_in[18];

  float* out = (float*)d_out;
  char* ws = (char*)d_ws;
  u16* xl1  = (u16*)ws;                         // 6291456 B
  u16* xl2  = (u16*)(ws + 6291456);             // 6291456 B
  u16* o2a  = (u16*)(ws + 12582912);            // 25165824 B
  u16* Bp1  = (u16*)(ws + 37748736);
  u16* Bp2a = (u16*)(ws + 37773312);
  u16* Bp2b = (u16*)(ws + 37847040);
  float* bnp1  = (float*)(ws + 37920768);
  float* bnp2a = (float*)(ws + 37921152);
  float* bnp2b = (float*)(ws + 37921536);

  setup_all_kernel<<<dim3(144, 3), 256, 0, stream>>>(
      w1, b1, g1, be1, m1, v1, Bp1, bnp1,
      w2a, b2a, g2a, be2a, m2a, v2a, Bp2a, bnp2a,
      w2b, b2b, g2b, be2b, m2b, v2b, Bp2b, bnp2b);

  dwt_fused_kernel<<<768, 256, 0, stream>>>(x, xl1, xl2);

  // conv1: (16,12,128,128) -> out ch 0..47 (fp32)
  convt_mfma<12, 16, 128, 128, false><<<dim3(2, 32, 16), 256, 0, stream>>>(
      xl1, Bp1, bnp1, out, 96, 0);
  // conv2a: (16,48,64,64) -> o2a (bf16)
  convt_mfma<48, 48, 64, 64, true><<<dim3(1, 16, 16), 256, 0, stream>>>(
      xl2, Bp2a, bnp2a, o2a, 48, 0);
  // conv2b: (16,48,128,128) -> out ch 48..95 (fp32)
  convt_mfma<48, 48, 128, 128, false><<<dim3(2, 32, 16), 256, 0, stream>>>(
      o2a, Bp2b, bnp2b, out, 96, 48);
}

// Round 8
// 119.996 us; speedup vs baseline: 4.5620x; 1.0910x over previous
//
#include <hip/hip_runtime.h>

typedef short s16x8 __attribute__((ext_vector_type(8)));
typedef float f32x4 __attribute__((ext_vector_type(4)));
typedef unsigned short u16;

#define BN_EPS 1e-5f

__device__ __forceinline__ u16 f2bf(float f) {
  union { float f; unsigned u; } v; v.f = f;
  unsigned r = (v.u + 0x7fffu + ((v.u >> 16) & 1u)) >> 16;
  return (u16)r;
}

// -------- setup helper: pack per-lane B fragments + BN (inv, shift) --------
__device__ void setup_one(
    const float* __restrict__ w, const float* __restrict__ bias,
    const float* __restrict__ g, const float* __restrict__ be,
    const float* __restrict__ mu, const float* __restrict__ var,
    u16* __restrict__ Bp, float* __restrict__ bnp,
    int CIN, int CIP, int KSTEPS, int e)
{
  if (e < 48) {
    float iv = g[e] * rsqrtf(var[e] + BN_EPS);
    bnp[e] = iv;
    bnp[48 + e] = (bias[e] - mu[e]) * iv + be[e];
  }
  int total = 4 * KSTEPS * 1536;
  if (e >= total) return;
  int j = e & 7;
  int l = (e >> 3) & 63;
  int nt = (e >> 9) % 3;
  int sp = e / 1536;
  int s = sp % KSTEPS;
  int p = sp / KSTEPS;
  int py = p >> 1, px = p & 1;
  int n = nt * 16 + (l & 15);
  int k = s * 32 + (l >> 4) * 8 + j;
  int tap = k / CIP, ci = k % CIP;
  int kh = 2 * (tap >> 1) + 1 - py;
  int kw = 2 * (tap & 1) + 1 - px;
  float v = (ci < CIN) ? w[((ci * 48 + n) * 4 + kh) * 4 + kw] : 0.f;
  Bp[e] = f2bf(v);
}

// -------- fused prep: DWT l1+l2 (blocks 0..767) + weight packing (768+) ----
__global__ __launch_bounds__(256) void prep_kernel(
    const float* __restrict__ x, u16* __restrict__ xl1, u16* __restrict__ xl2,
    const float* w1, const float* b1, const float* g1, const float* be1,
    const float* m1, const float* v1, u16* Bp1, float* bnp1,
    const float* w2a, const float* b2a, const float* g2a, const float* be2a,
    const float* m2a, const float* v2a, u16* Bp2a, float* bnp2a,
    const float* w2b, const float* b2b, const float* g2b, const float* be2b,
    const float* m2b, const float* v2b, u16* Bp2b, float* bnp2b)
{
  if (blockIdx.x >= 768) {
    int sub = blockIdx.x - 768;           // 432 blocks: 144 per conv
    int which = sub / 144;
    int e = (sub % 144) * 256 + threadIdx.x;
    if (which == 0)      setup_one(w1, b1, g1, be1, m1, v1, Bp1, bnp1, 12, 16, 2, e);
    else if (which == 1) setup_one(w2a, b2a, g2a, be2a, m2a, v2a, Bp2a, bnp2a, 48, 48, 6, e);
    else                 setup_one(w2b, b2b, g2b, be2b, m2b, v2b, Bp2b, bnp2b, 48, 48, 6, e);
    return;
  }
  int idx = blockIdx.x * 256 + threadIdx.x;   // 16*3*64*64 = 196608
  int w4 = idx & 63; int t = idx >> 6;
  int h4 = t & 63; t >>= 6;
  int c = t % 3; int b = t / 3;
  const float* p = x + (((long)(b * 3 + c) * 256 + 4 * h4) * 256 + 4 * w4);
  float4 r0 = *(const float4*)p;
  float4 r1 = *(const float4*)(p + 256);
  float4 r2 = *(const float4*)(p + 512);
  float4 r3 = *(const float4*)(p + 768);
  float rows[4][4] = {{r0.x, r0.y, r0.z, r0.w}, {r1.x, r1.y, r1.z, r1.w},
                      {r2.x, r2.y, r2.z, r2.w}, {r3.x, r3.y, r3.z, r3.w}};
  float sb[4][2][2];
  #pragma unroll
  for (int qy = 0; qy < 2; ++qy)
    #pragma unroll
    for (int qx = 0; qx < 2; ++qx) {
      float a = rows[2 * qy][2 * qx],      bb = rows[2 * qy][2 * qx + 1];
      float cc = rows[2 * qy + 1][2 * qx], dd = rows[2 * qy + 1][2 * qx + 1];
      sb[0][qy][qx] = (a + bb + cc + dd) * 0.5f;
      sb[1][qy][qx] = (a + bb - cc - dd) * 0.5f;
      sb[2][qy][qx] = (a - bb + cc - dd) * 0.5f;
      sb[3][qy][qx] = (a - bb - cc + dd) * 0.5f;
    }
  #pragma unroll
  for (int s = 0; s < 4; ++s)
    #pragma unroll
    for (int qy = 0; qy < 2; ++qy) {
      unsigned pk = (unsigned)f2bf(sb[s][qy][0]) | ((unsigned)f2bf(sb[s][qy][1]) << 16);
      *(unsigned*)&xl1[(((long)(b * 12 + 4 * c + s) * 128) + 2 * h4 + qy) * 128 + 2 * w4] = pk;
    }
  #pragma unroll
  for (int s = 0; s < 4; ++s) {
    float a = sb[s][0][0], bb = sb[s][0][1], cc = sb[s][1][0], dd = sb[s][1][1];
    float o[4] = {(a + bb + cc + dd) * 0.5f, (a + bb - cc - dd) * 0.5f,
                  (a - bb + cc - dd) * 0.5f, (a - bb - cc + dd) * 0.5f};
    #pragma unroll
    for (int s2 = 0; s2 < 4; ++s2)
      xl2[(((long)(b * 48 + (4 * c + s) * 4 + s2) * 64) + h4) * 64 + w4] = f2bf(o[s2]);
  }
}

// -------- ConvT(4,2,1)+BN+ReLU via MFMA implicit GEMM ----------------------
// Block: 32x4 input quads (64x8 output) x all 48 co. 4 waves = 4 parities.
// 35.1KB LDS (CIP=48) -> 4 blocks/CU target; B-fragments reloaded from L1.
template<int CIN, int CIP, int HIN, int WIN, bool OBF16>
__global__ __launch_bounds__(256, 4) void convt_mfma(
    const u16* __restrict__ in,    // (B, CIN, HIN, WIN) bf16
    const u16* __restrict__ Bp,    // packed B fragments
    const float* __restrict__ bnp, // inv[48], sh[48]
    void* __restrict__ outv, int outc, int obase)
{
  constexpr int KSTEPS = CIP / 8;
  constexpr int ITX = 34, ITY = 6;
  constexpr int HOUT = 2 * HIN, WOUT = 2 * WIN;
  __shared__ __align__(16) u16 in_lds[ITX * ITY * CIP];
  __shared__ __align__(16) float out_lds[32 * 2 * 64];

  const int tid = threadIdx.x;
  const int n = blockIdx.z;
  const int qY0 = blockIdx.y * 4;
  const int qX0 = blockIdx.x * 32;

  // ---- stage input tile [y][x][ci_rot], 16B loads + halo ----
  {
    constexpr int NTASK = CIP * ITY * 4;
    for (int t = tid; t < NTASK; t += 256) {
      int seg = t & 3;
      int rowid = t >> 2;
      int ci = rowid / ITY;
      int y = rowid - ci * ITY;
      int ih = qY0 - 1 + y;
      bool rowok = (CIP == CIN || ci < CIN) && ((unsigned)ih < (unsigned)HIN);
      const u16* gsrc = in + (((long)n * CIN + ci) * HIN + ih) * WIN + qX0 + 8 * seg;
      s16x8 v = {0, 0, 0, 0, 0, 0, 0, 0};
      if (rowok) v = *(const s16x8*)gsrc;
      int base_yx = y * ITX;
      #pragma unroll
      for (int j = 0; j < 8; ++j) {
        int xx = 1 + 8 * seg + j;
        int rot = 8 * ((xx >> 2) & 3);
        if (rot >= CIP) rot -= CIP;
        int cr = ci + rot;
        if (cr >= CIP) cr -= CIP;
        in_lds[(base_yx + xx) * CIP + cr] = (u16)v[j];
      }
      if (seg == 0 || seg == 3) {
        int xh = (seg == 0) ? 0 : 33;
        int iwh = qX0 - 1 + xh;
        u16 hv = 0;
        if (rowok && (unsigned)iwh < (unsigned)WIN) hv = gsrc[(seg == 0) ? -1 : 8];
        int rot = 8 * ((xh >> 2) & 3);
        if (rot >= CIP) rot -= CIP;
        int cr = ci + rot;
        if (cr >= CIP) cr -= CIP;
        in_lds[(base_yx + xh) * CIP + cr] = hv;
      }
    }
  }

  const int wid = tid >> 6, lane = tid & 63;
  const int py = wid >> 1, px = wid & 1;
  const int g = lane >> 4, qx = lane & 15;

  const s16x8* bpp = (const s16x8*)Bp + (wid * KSTEPS * 3) * 64 + lane;

  // ---- BN params per lane: co = nt*16 + 4*g + r ----
  float4 inv4[3], sh4[3];
  #pragma unroll
  for (int nt = 0; nt < 3; ++nt) {
    inv4[nt] = *(const float4*)&bnp[nt * 16 + 4 * g];
    sh4[nt]  = *(const float4*)&bnp[48 + nt * 16 + 4 * g];
  }

  // ---- per-kstep A-read base (mc=0, mt=0) ----
  int abase[KSTEPS];
  #pragma unroll
  for (int s = 0; s < KSTEPS; ++s) {
    int k0 = s * 32 + g * 8;
    int tap = k0 / CIP, ci0 = k0 - tap * CIP;
    int ty = tap >> 1, tx = tap & 1;
    int y = 1 + py - ty;
    int xx = qx + 1 + px - tx;
    int rot = 8 * ((xx >> 2) & 3);
    if (rot >= CIP) rot -= CIP;
    int cr = ci0 + rot;
    if (cr >= CIP) cr -= CIP;
    abase[s] = (y * ITX + xx) * CIP + cr;
  }

  __syncthreads();

  for (int mc = 0; mc < 4; ++mc) {
    f32x4 acc[2][3];
    #pragma unroll
    for (int mt = 0; mt < 2; ++mt)
      #pragma unroll
      for (int nt = 0; nt < 3; ++nt)
        acc[mt][nt] = f32x4{0.f, 0.f, 0.f, 0.f};

    #pragma unroll
    for (int s = 0; s < KSTEPS; ++s) {
      s16x8 bf0 = bpp[(s * 3 + 0) * 64];
      s16x8 bf1 = bpp[(s * 3 + 1) * 64];
      s16x8 bf2 = bpp[(s * 3 + 2) * 64];
      #pragma unroll
      for (int mt = 0; mt < 2; ++mt) {
        s16x8 a = *(const s16x8*)&in_lds[abase[s] + (mc * ITX + mt * 16) * CIP];
        acc[mt][0] = __builtin_amdgcn_mfma_f32_16x16x32_bf16(bf0, a, acc[mt][0], 0, 0, 0);
        acc[mt][1] = __builtin_amdgcn_mfma_f32_16x16x32_bf16(bf1, a, acc[mt][1], 0, 0, 0);
        acc[mt][2] = __builtin_amdgcn_mfma_f32_16x16x32_bf16(bf2, a, acc[mt][2], 0, 0, 0);
      }
    }

    // ---- epilogue: two co-subchunks: {nt 0,1 -> 32 co}, {nt 2 -> 16 co} --
    #pragma unroll
    for (int sc = 0; sc < 2; ++sc) {
      const int ntlo = (sc == 0) ? 0 : 2;
      const int ntn  = (sc == 0) ? 2 : 1;
      const int coBase = ntlo * 16;
      __syncthreads();   // out_lds free
      #pragma unroll
      for (int ntl = 0; ntl < 2; ++ntl) {
        if (ntl < ntn) {
          const int nt = ntlo + ntl;
          #pragma unroll
          for (int mt = 0; mt < 2; ++mt) {
            #pragma unroll
            for (int r = 0; r < 4; ++r) {
              const int co_rel = ntl * 16 + 4 * g + r;
              float iv = ((const float*)&inv4[nt])[r];
              float sv = ((const float*)&sh4[nt])[r];
              float val = fmaxf(acc[mt][nt][r] * iv + sv, 0.f);
              out_lds[(co_rel * 2 + py) * 64 + 2 * (mt * 16 + qx) + px] = val;
            }
          }
        }
      }
      __syncthreads();   // out_lds filled
      // float4 elems: ntn*16 co * 2 parities * 16 per row = ntn*512
      const int nIter = ntn * 2;
      #pragma unroll
      for (int u = 0; u < 4; ++u) {
        if (u < nIter) {
          int e = u * 256 + tid;
          int ow4 = e & 15, row = e >> 4;
          int co_l = coBase + (row >> 1), ohp = row & 1;
          f32x4 vv = *(const f32x4*)&out_lds[row * 64 + 4 * ow4];
          long off = (((long)(n * outc + obase + co_l) * HOUT + 2 * (qY0 + mc) + ohp) * WOUT)
                     + 2 * qX0 + 4 * ow4;
          if (OBF16) {
            unsigned lo = (unsigned)f2bf(vv.x) | ((unsigned)f2bf(vv.y) << 16);
            unsigned hi = (unsigned)f2bf(vv.z) | ((unsigned)f2bf(vv.w) << 16);
            uint2 pk; pk.x = lo; pk.y = hi;
            *(uint2*)((u16*)outv + off) = pk;
          } else {
            __builtin_nontemporal_store(vv, (f32x4*)((float*)outv + off));
          }
        }
      }
    }
  }
}

extern "C" void kernel_launch(void* const* d_in, const int* in_sizes, int n_in,
                              void* d_out, int out_size, void* d_ws, size_t ws_size,
                              hipStream_t stream) {
  const float* x    = (const float*)d_in[0];
  const float* w1   = (const float*)d_in[1];
  const float* b1   = (const float*)d_in[2];
  const float* g1   = (const float*)d_in[3];
  const float* be1  = (const float*)d_in[4];
  const float* m1   = (const float*)d_in[5];
  const float* v1   = (const float*)d_in[6];
  const float* w2a  = (const float*)d_in[7];
  const float* b2a  = (const float*)d_in[8];
  const float* g2a  = (const float*)d_in[9];
  const float* be2a = (const float*)d_in[10];
  const float* m2a  = (const float*)d_in[11];
  const float* v2a  = (const float*)d_in[12];
  const float* w2b  = (const float*)d_in[13];
  const float* b2b  = (const float*)d_in[14];
  const float* g2b  = (const float*)d_in[15];
  const float* be2b = (const float*)d_in[16];
  const float* m2b  = (const float*)d_in[17];
  const float* v2b  = (const float*)d_in[18];

  float* out = (float*)d_out;
  char* ws = (char*)d_ws;
  u16* xl1  = (u16*)ws;                         // 6291456 B
  u16* xl2  = (u16*)(ws + 6291456);             // 6291456 B
  u16* o2a  = (u16*)(ws + 12582912);            // 25165824 B
  u16* Bp1  = (u16*)(ws + 37748736);
  u16* Bp2a = (u16*)(ws + 37773312);
  u16* Bp2b = (u16*)(ws + 37847040);
  float* bnp1  = (float*)(ws + 37920768);
  float* bnp2a = (float*)(ws + 37921152);
  float* bnp2b = (float*)(ws + 37921536);

  // fused: dwt l1+l2 (768 blocks) + 3x setup (432 blocks)
  prep_kernel<<<1200, 256, 0, stream>>>(
      x, xl1, xl2,
      w1, b1, g1, be1, m1, v1, Bp1, bnp1,
      w2a, b2a, g2a, be2a, m2a, v2a, Bp2a, bnp2a,
      w2b, b2b, g2b, be2b, m2b, v2b, Bp2b, bnp2b);

  // conv2a: (16,48,64,64) -> o2a (bf16)
  convt_mfma<48, 48, 64, 64, true><<<dim3(2, 16, 16), 256, 0, stream>>>(
      xl2, Bp2a, bnp2a, o2a, 48, 0);
  // conv1: (16,12,128,128) -> out ch 0..47 (fp32)
  convt_mfma<12, 16, 128, 128, false><<<dim3(4, 32, 16), 256, 0, stream>>>(
      xl1, Bp1, bnp1, out, 96, 0);
  // conv2b: (16,48,128,128) -> out ch 48..95 (fp32)
  convt_mfma<48, 48, 128, 128, false><<<dim3(4, 32, 16), 256, 0, stream>>>(
      o2a, Bp2b, bnp2b, out, 96, 48);
}